// Round 13
// baseline (4045.713 us; speedup 1.0000x reference)
//
#include <hip/hip_runtime.h>
#include <math.h>

#define LSTRIDE 4194304   // 4096*1024

// --- fast device math (scan only; precompute uses precise libm) ---
__device__ __forceinline__ float fast_tanh(float x) {
  x = fminf(9.f, fmaxf(-9.f, x));
  float e = __expf(2.f * x);
  return (e - 1.f) * __builtin_amdgcn_rcpf(e + 1.f);
}
__device__ __forceinline__ float fsig(float x) {
  return __builtin_amdgcn_rcpf(1.f + __expf(-x));
}
__device__ __forceinline__ float sigp(float x) { return 1.0f / (1.0f + expf(-x)); }

// Coherent (L2-bypassing) access for ALL cross-WG data => no fences needed.
__device__ __forceinline__ float cload(const float* p) {
  return __hip_atomic_load(p, __ATOMIC_RELAXED, __HIP_MEMORY_SCOPE_AGENT);
}
__device__ __forceinline__ void cstore(float* p, float v) {
  __hip_atomic_store(p, v, __ATOMIC_RELAXED, __HIP_MEMORY_SCOPE_AGENT);
}
__device__ __forceinline__ float2 cload2(const float* p) {
  unsigned long long v = __hip_atomic_load((const unsigned long long*)p,
                                           __ATOMIC_RELAXED, __HIP_MEMORY_SCOPE_AGENT);
  float2 r;
  r.x = __uint_as_float((unsigned)v);
  r.y = __uint_as_float((unsigned)(v >> 32));
  return r;
}
__device__ __forceinline__ void cstore2(float* p, float2 v) {
  unsigned long long u = ((unsigned long long)__float_as_uint(v.y) << 32) |
                         (unsigned long long)__float_as_uint(v.x);
  __hip_atomic_store((unsigned long long*)p, u, __ATOMIC_RELAXED, __HIP_MEMORY_SCOPE_AGENT);
}

// ---------------------------------------------------------------------------
// Fast GEMM: Out[m*ldo+n] = sum_k A[n*1024+k]*X[m*ldx+k] (+b1[n]+b2[n])
// K fixed = 1024. 128x128 tile, BK=16, 256 threads, 8x8 per thread.
// Grid: (N/128, ceil(M/128)). N must be a multiple of 128 and <= A's rows.
// ---------------------------------------------------------------------------
__global__ __launch_bounds__(256) void gemm128(
    const float* __restrict__ A, const float* __restrict__ X, float* __restrict__ Out,
    const float* __restrict__ b1, const float* __restrict__ b2,
    int M, int ldx, int ldo)
{
  __shared__ float As[16][128];
  __shared__ float Xs[16][128];
  const int tid = threadIdx.x;
  const int tx = tid & 15, ty = tid >> 4;
  const int bn = blockIdx.x * 128, bm = blockIdx.y * 128;
  float acc[8][8];
  #pragma unroll
  for (int i = 0; i < 8; ++i)
    #pragma unroll
    for (int j = 0; j < 8; ++j) acc[i][j] = 0.f;

  for (int k0 = 0; k0 < 1024; k0 += 16) {
    #pragma unroll
    for (int v = 0; v < 2; ++v) {
      int idx = tid + v * 256;            // 0..511 float4 slots
      int row = idx >> 2, kq = (idx & 3) << 2;
      float4 a4 = *(const float4*)(A + (size_t)(bn + row) * 1024 + k0 + kq);
      As[kq + 0][row] = a4.x; As[kq + 1][row] = a4.y;
      As[kq + 2][row] = a4.z; As[kq + 3][row] = a4.w;
      float4 x4 = make_float4(0.f, 0.f, 0.f, 0.f);
      if (bm + row < M) x4 = *(const float4*)(X + (size_t)(bm + row) * ldx + k0 + kq);
      Xs[kq + 0][row] = x4.x; Xs[kq + 1][row] = x4.y;
      Xs[kq + 2][row] = x4.z; Xs[kq + 3][row] = x4.w;
    }
    __syncthreads();
    #pragma unroll
    for (int kk = 0; kk < 16; ++kk) {
      float regN[8], regM[8];
      #pragma unroll
      for (int j = 0; j < 8; ++j) regN[j] = As[kk][tx * 8 + j];
      #pragma unroll
      for (int i = 0; i < 8; ++i) regM[i] = Xs[kk][ty * 8 + i];
      #pragma unroll
      for (int i = 0; i < 8; ++i)
        #pragma unroll
        for (int j = 0; j < 8; ++j) acc[i][j] += regM[i] * regN[j];
    }
    __syncthreads();
  }
  #pragma unroll
  for (int i = 0; i < 8; ++i) {
    int m = bm + ty * 8 + i;
    if (m >= M) continue;
    #pragma unroll
    for (int j = 0; j < 8; ++j) {
      int n = bn + tx * 8 + j;
      float r = acc[i][j];
      if (b1) r += b1[n] + b2[n];
      Out[(size_t)m * ldo + n] = r;
    }
  }
}

__global__ void diag_k(const float* __restrict__ wh, const float* __restrict__ wht,
                       float* __restrict__ diag)
{
  int i = blockIdx.x * 256 + threadIdx.x;
  if (i < 2048) {
    int l = i >> 10, h = i & 1023;
    size_t idx = (size_t)l * 1048576 + (size_t)h * 1025;
    diag[i]        = wh[idx];
    diag[2048 + i] = wht[idx];
  }
}

__global__ __launch_bounds__(256) void phase1_l0_k(const float* __restrict__ XI0,
    float* __restrict__ tapeh, float* __restrict__ tapec, float* __restrict__ h0p1)
{
  int t = blockIdx.x;
  #pragma unroll
  for (int r = 0; r < 4; ++r) {
    int c = threadIdx.x + r * 256;
    float gi = XI0[t*4096 + c];
    float gg = XI0[t*4096 + 2048 + c];
    float go = XI0[t*4096 + 3072 + c];
    float cc = sigp(gi) * tanhf(gg);
    float hh = sigp(go) * tanhf(cc);
    tapeh[t*2048 + c] = hh;
    tapec[t*2048 + c] = cc;
    h0p1[t*1024 + c] = hh;
  }
}

__global__ __launch_bounds__(256) void phase1_l1_k(const float* __restrict__ G1,
    float* __restrict__ tapeh, float* __restrict__ tapec)
{
  int t = blockIdx.x;
  #pragma unroll
  for (int r = 0; r < 4; ++r) {
    int c = threadIdx.x + r * 256;
    float gi = G1[t*4096 + c];
    float gg = G1[t*4096 + 2048 + c];
    float go = G1[t*4096 + 3072 + c];
    float cc = sigp(gi) * tanhf(gg);
    float hh = sigp(go) * tanhf(cc);
    tapeh[t*2048 + 1024 + c] = hh;
    tapec[t*2048 + 1024 + c] = cc;
  }
}

__device__ __forceinline__ float red16(float p) {
  #pragma unroll
  for (int o = 8; o >= 1; o >>= 1) p += __shfl_xor(p, o, 16);
  return p;
}

// ---------------------------------------------------------------------------
// Barrier per group (base stride 256 u32): 8 L1-counters at base[i*16]
// (16 WGs each), flag-counter at base[128]. Flag value after gen g = 8*g.
// Gen g: bootstrap = 1, scan step t completed = t-28.
// ---------------------------------------------------------------------------
__device__ __forceinline__ void arrive(unsigned* __restrict__ base, int gw) {
  asm volatile("s_waitcnt vmcnt(0)" ::: "memory");
  __syncthreads();
  if (threadIdx.x == 0) {
    unsigned o = __hip_atomic_fetch_add(&base[(gw >> 4) * 16], 1u,
                                        __ATOMIC_RELAXED, __HIP_MEMORY_SCOPE_AGENT);
    if (((o + 1) & 15u) == 0u)
      __hip_atomic_fetch_add(&base[128], 1u,
                             __ATOMIC_RELAXED, __HIP_MEMORY_SCOPE_AGENT);
  }
}

__device__ __forceinline__ void waitf(const unsigned* __restrict__ fOwn, unsigned tOwn,
                                      const unsigned* __restrict__ fOth, unsigned tOth) {
  if (threadIdx.x < 2) {
    const unsigned* fp = threadIdx.x ? fOth : fOwn;
    unsigned tgt = threadIdx.x ? tOth : tOwn;
    if (tgt) {
      while (__hip_atomic_load(fp, __ATOMIC_RELAXED, __HIP_MEMORY_SCOPE_AGENT) < tgt)
        __builtin_amdgcn_s_sleep(1);
    }
  }
  __syncthreads();
  asm volatile("" ::: "memory");
}

// ---------------------------------------------------------------------------
// Pipelined persistent scan (round-9 structure, verified). LW=0: WGs 0..127
// (layer-0 chain, barrier group 0). LW=1: WGs 128..255 (layer-1, one step
// behind, barrier group 1). 58 score WGs/group: slot ii=gw>>1, half=gw&1.
// ---------------------------------------------------------------------------
template <int LW>
__device__ __forceinline__ void run_group(
    const int gw,
    const float* __restrict__ wih, const float* __restrict__ whh,
    const float* __restrict__ bih, const float* __restrict__ bhh,
    const float* __restrict__ diag, const float* __restrict__ av,
    const float* __restrict__ XI0, const float* __restrict__ XA,
    const float* __restrict__ tapehG, const float* __restrict__ tapecG,
    const float* __restrict__ Pg,
    float* __restrict__ scoresG, float* __restrict__ prevh,
    float* __restrict__ h0cur, float* __restrict__ h1cur,
    float* __restrict__ outp, unsigned* __restrict__ bar,
    float* tape, float* hA, float* hB, float* Pl, float* tc,
    float* sc2, float* aw, float* gls, float* ihs, float* ncs,
    float* bsum, float* sred)
{
  const int tid = threadIdx.x;
  const int rid = tid >> 4, sub = tid & 15;       // 32 row-slots x 16 lanes
  const int row = ((rid >> 3) << 10) + (gw << 3) + (rid & 7);
  const bool isScore = (gw < 58);
  const int ii = gw >> 1, half = gw & 1;
  const int d = (half << 9) + tid;                // this thread's tail dim
  const int h2 = tid * 2;

  unsigned* __restrict__ barOwn = bar + (LW ? 256 : 0);
  const unsigned* __restrict__ fOwn = barOwn + 128;
  const unsigned* __restrict__ fOth = bar + (LW ? 0 : 256) + 128;

  // ---- one-time init: weights -> VGPRs, P/tape/tc -> LDS ----
  float wA[64];
  float wB[LW ? 64 : 1];
  {
    const float* pa = whh + (size_t)LW * LSTRIDE + (size_t)row * 1024 + sub * 64;
    #pragma unroll
    for (int i = 0; i < 16; ++i) {
      float4 v = ((const float4*)pa)[i];
      wA[4*i] = v.x; wA[4*i+1] = v.y; wA[4*i+2] = v.z; wA[4*i+3] = v.w;
    }
    if (LW) {
      const float* pb = wih + LSTRIDE + (size_t)row * 1024 + sub * 64;
      #pragma unroll
      for (int i = 0; i < 16; ++i) {
        float4 v = ((const float4*)pb)[i];
        wB[4*i] = v.x; wB[4*i+1] = v.y; wB[4*i+2] = v.z; wB[4*i+3] = v.w;
      }
    }
  }
  if (LW && sub == 0) bsum[rid] = bih[4096 + row] + bhh[4096 + row];
  for (int k = tid; k < 960; k += 512) {
    int s = k >> 5, r = k & 31;
    int rr = ((r >> 3) << 10) + (gw << 3) + (r & 7);
    Pl[s * 34 + r] = Pg[s * 4096 + rr];
  }
  for (int k = tid; k < 240; k += 512) {
    int s = k >> 3, c = k & 7;
    tc[s * 9 + c] = tapecG[s * 2048 + LW * 1024 + (gw << 3) + c];
  }
  if (isScore) {
    for (int k = tid; k < 3840; k += 512) {       // 30 slots x 512 dims / 4
      int s = k >> 7, off = (k & 127) << 2;
      *(float4*)&tape[s * 512 + off] =
          *(const float4*)&tapehG[s * 2048 + LW * 1024 + (half << 9) + off];
    }
  }
  // per-thread attn constants: full-dim pair (new-slot) + tail dim d
  const float ddx = diag[LW*1024 + h2],        ddy = diag[LW*1024 + h2 + 1];
  const float ttx = diag[2048 + LW*1024 + h2], tty = diag[2048 + LW*1024 + h2 + 1];
  const float vvx = av[LW*1024 + h2],          vvy = av[LW*1024 + h2 + 1];
  const float ddT = diag[LW*1024 + d];
  const float ttT = diag[2048 + LW*1024 + d];
  const float vvT = av[LW*1024 + d];
  __syncthreads();

  // ---- bootstrap: score partials for t=30 (prev_h = 0) ----
  if (isScore) {
    for (int s = ii; s < 30; s += 29) {
      float xa = XA[(size_t)30 * 2048 + LW * 1024 + d];
      float part = vvT * fast_tanh(ddT * tape[s * 512 + tid] + xa);
      #pragma unroll
      for (int o = 32; o >= 1; o >>= 1) part += __shfl_xor(part, o, 64);
      if ((tid & 63) == 0) sred[tid >> 6] = part;
      __syncthreads();
      if (tid == 0) {
        float tot = 0.f;
        #pragma unroll
        for (int i = 0; i < 8; ++i) tot += sred[i];
        cstore(&scoresG[LW * 64 + 2 * s + half], tot);
      }
      __syncthreads();
    }
  }
  arrive(barOwn, gw);   // gen 1

  for (int t = 30; t < 512; ++t) {
    // ---- prefetch (flag-independent, hides under the wait) ----
    float2 xan = make_float2(0.f, 0.f);
    if (t > 30) xan = *(const float2*)&XA[(size_t)t * 2048 + LW * 1024 + h2];
    float xi = 0.f;
    if (LW == 0 && sub == 0) xi = XI0[(size_t)t * 4096 + row];
    float xaT = 0.f;
    if (isScore && t < 511) xaT = XA[(size_t)(t + 1) * 2048 + LW * 1024 + d];

    // ---- wait (verified generation targets) ----
    unsigned tOwn = 8u * (unsigned)(t - 29);
    unsigned tOth;
    if (LW == 0)
      tOth = (t >= 34) ? 8u * (unsigned)(t - 32) : 0u;  // L1 consumed h0(t-4)
    else
      tOth = 8u * (unsigned)(t - 28);                   // L0 completed t
    waitf(fOwn, tOwn, fOth, tOth);

    const int tmod = t % 30;
    const int pslot = (tmod == 0) ? 29 : tmod - 1;

    // ---- coherent gather ----
    if (tid < 60) sc2[tid] = cload(&scoresG[(t & 1) * 128 + LW * 64 + tid]);
    float2 hva = make_float2(0.f, 0.f), hvb = make_float2(0.f, 0.f),
           ph = make_float2(0.f, 0.f);
    if (LW == 0) {
      if (t > 30) hva = cload2(&h0cur[(size_t)((t - 1) & 3) * 1024 + h2]);
    } else {
      hva = cload2(&h0cur[(size_t)(t & 3) * 1024 + h2]);           // h0(t)
      if (t > 30) hvb = cload2(&h1cur[((t - 1) & 1) * 1024 + h2]); // h1(t-1)
    }
    if (t > 30) ph = cload2(&prevh[((t - 1) & 1) * 2048 + LW * 1024 + h2]);
    {
      int o = (h2 >> 6) * 66 + (h2 & 63);
      if (LW || t > 30) { hA[o] = hva.x; hA[o + 1] = hva.y; }
      if (LW && t > 30) { hB[o] = hvb.x; hB[o + 1] = hvb.y; }
    }
    __syncthreads();

    // ---- new-slot score + tape refresh + P-col matvec (+ ih for L1) ----
    if (t > 30) {
      float2 hn = LW ? hvb : hva;                 // own-layer h(t-1)
      float np = vvx * fast_tanh(ddx * hn.x + xan.x + ttx * ph.x)
               + vvy * fast_tanh(ddy * hn.y + xan.y + tty * ph.y);
      #pragma unroll
      for (int o = 32; o >= 1; o >>= 1) np += __shfl_xor(np, o, 64);
      if ((tid & 63) == 0) sred[tid >> 6] = np;
      if (isScore) {
        int loc = h2 - (half << 9);
        if ((unsigned)loc < 512u) {
          tape[pslot * 512 + loc]     = hn.x;
          tape[pslot * 512 + loc + 1] = hn.y;
        }
      }
      const float* hp = LW ? hB : hA;
      float pc = 0.f;
      #pragma unroll
      for (int i = 0; i < 64; ++i) pc += wA[i] * hp[sub * 66 + i];
      pc = red16(pc);
      if (sub == 0) Pl[pslot * 34 + rid] = pc;
    }
    if (LW) {
      float ih = 0.f;
      #pragma unroll
      for (int i = 0; i < 64; ++i) ih += wB[i] * hA[sub * 66 + i];
      ih = red16(ih);
      if (sub == 0) ihs[rid] = ih + bsum[rid];
    }
    __syncthreads();

    // ---- softmax (wave 0; sum half-partials; fold in new-slot score) ----
    if (tid < 32) {
      float npv = 0.f;
      if (t > 30) {
        float x = (tid < 8) ? sred[tid] : 0.f;
        #pragma unroll
        for (int o = 4; o >= 1; o >>= 1) x += __shfl_xor(x, o, 8);
        npv = __shfl(x, 0, 32);
      }
      float v = (tid < 30) ? sc2[2 * tid] + sc2[2 * tid + 1] : -1e30f;
      if (t > 30 && tid == pslot) v = npv;
      float m = v;
      #pragma unroll
      for (int o = 16; o >= 1; o >>= 1) m = fmaxf(m, __shfl_xor(m, o, 32));
      float e = (tid < 30) ? __expf(v - m) : 0.f;
      float sm = e;
      #pragma unroll
      for (int o = 16; o >= 1; o >>= 1) sm += __shfl_xor(sm, o, 32);
      aw[tid] = e * __builtin_amdgcn_rcpf(sm);
    }
    __syncthreads();

    // ---- gates (alpha-weighted P) + c-tape sums ----
    {
      float p = aw[sub] * Pl[sub * 34 + rid];
      if (sub < 14) p += aw[sub + 16] * Pl[(sub + 16) * 34 + rid];
      p = red16(p);
      if (sub == 0) gls[rid] = p + (LW ? ihs[rid] : xi);
      if (rid < 8) {
        float pn = aw[sub] * tc[sub * 9 + rid];
        if (sub < 14) pn += aw[sub + 16] * tc[(sub + 16) * 9 + rid];
        pn = red16(pn);
        if (sub == 0) ncs[rid] = pn;
      }
    }
    __syncthreads();

    // ---- LSTM cell + publish ----
    if (tid < 8) {
      float gi = gls[tid], gf = gls[8 + tid], gg = gls[16 + tid], go = gls[24 + tid];
      float cv = fsig(gf) * ncs[tid] + fsig(gi) * fast_tanh(gg);
      float hv = fsig(go) * fast_tanh(cv);
      if (LW == 0) {
        cstore(&h0cur[(size_t)(t & 3) * 1024 + (gw << 3) + tid], hv);
      } else {
        outp[(size_t)(t - 30) * 1024 + (gw << 3) + tid] = hv;
        cstore(&h1cur[(t & 1) * 1024 + (gw << 3) + tid], hv);
      }
      tc[tmod * 9 + tid] = cv;
    }

    // ---- score-WG tail: prevh(t) half + one old-slot score partial ----
    if (isScore && t < 511) {
      int ss = tmod + 1 + ii; if (ss >= 30) ss -= 30;
      float acc = 0.f;
      #pragma unroll
      for (int s = 0; s < 30; ++s) acc += aw[s] * tape[s * 512 + tid];
      if (ii == 0) cstore(&prevh[(t & 1) * 2048 + LW * 1024 + d], acc);
      float part = vvT * fast_tanh(ddT * tape[ss * 512 + tid] + xaT + ttT * acc);
      #pragma unroll
      for (int o = 32; o >= 1; o >>= 1) part += __shfl_xor(part, o, 64);
      if ((tid & 63) == 0) sred[tid >> 6] = part;
      __syncthreads();
      if (tid == 0) {
        float tot = 0.f;
        #pragma unroll
        for (int i = 0; i < 8; ++i) tot += sred[i];
        cstore(&scoresG[((t + 1) & 1) * 128 + LW * 64 + 2 * ss + half], tot);
      }
    }

    arrive(barOwn, gw);   // gen t-28
  }
}

__global__ __launch_bounds__(512, 2) void scan_fused(
    const float* __restrict__ wih, const float* __restrict__ whh,
    const float* __restrict__ bih, const float* __restrict__ bhh,
    const float* __restrict__ diag, const float* __restrict__ av,
    const float* __restrict__ XI0, const float* __restrict__ XA,
    const float* __restrict__ tapehG, const float* __restrict__ tapecG,
    const float* __restrict__ P0g, const float* __restrict__ P1g,
    float* __restrict__ scoresG, float* __restrict__ prevh,
    float* __restrict__ h0cur, float* __restrict__ h1cur,
    float* __restrict__ outp, unsigned* __restrict__ bar)
{
  __shared__ float tape[30 * 512];
  __shared__ float hA[16 * 66], hB[16 * 66];
  __shared__ float Pl[30 * 34];
  __shared__ float tc[30 * 9];
  __shared__ float sc2[64], aw[32], gls[32], ihs[32], ncs[8], bsum[32], sred[8];
  if (blockIdx.x < 128)
    run_group<0>(blockIdx.x, wih, whh, bih, bhh, diag, av, XI0, XA, tapehG, tapecG,
                 P0g, scoresG, prevh, h0cur, h1cur, outp, bar,
                 tape, hA, hB, Pl, tc, sc2, aw, gls, ihs, ncs, bsum, sred);
  else
    run_group<1>(blockIdx.x - 128, wih, whh, bih, bhh, diag, av, XI0, XA, tapehG, tapecG,
                 P1g, scoresG, prevh, h0cur, h1cur, outp, bar,
                 tape, hA, hB, Pl, tc, sc2, aw, gls, ihs, ncs, bsum, sred);
}

// ---------------------------------------------------------------------------
extern "C" void kernel_launch(void* const* d_in, const int* in_sizes, int n_in,
                              void* d_out, int out_size, void* d_ws, size_t ws_size,
                              hipStream_t stream) {
  (void)in_sizes; (void)n_in; (void)out_size; (void)ws_size;
  const float* xs    = (const float*)d_in[0];
  const float* w_ih  = (const float*)d_in[1];
  const float* w_hh  = (const float*)d_in[2];
  const float* b_ih  = (const float*)d_in[3];
  const float* b_hh  = (const float*)d_in[4];
  const float* a_wh  = (const float*)d_in[5];
  const float* a_wx  = (const float*)d_in[6];
  const float* a_wht = (const float*)d_in[7];
  const float* a_v   = (const float*)d_in[8];
  float* outp = (float*)d_out;

  float* ws     = (float*)d_ws;
  float* XI0    = ws;                      // 512*4096
  float* XA     = XI0    + 512 * 4096;     // 512*2048
  float* tapehG = XA     + 512 * 2048;     // 30*2048
  float* tapecG = tapehG + 30 * 2048;      // 30*2048
  float* P0g    = tapecG + 30 * 2048;      // 30*4096
  float* P1g    = P0g    + 30 * 4096;      // 30*4096
  float* diag   = P1g    + 30 * 4096;      // 4096
  float* scor   = diag   + 4096;           // 2 parity x 2 group x 64 = 256
  float* prevh  = scor   + 256;            // 2*2048
  float* h0cur  = prevh  + 4096;           // 4*1024 (depth-4)
  float* h1cur  = h0cur  + 4096;           // 2*1024
  float* h0p1   = h1cur  + 2048;           // 30*1024
  float* G1b    = h0p1   + 30 * 1024;      // 30*4096
  unsigned* bar = (unsigned*)(G1b + 30 * 4096);  // 2 groups x 256 u32

  hipMemsetAsync(outp + (size_t)482 * 1024, 0, 30 * 1024 * sizeof(float), stream);
  hipMemsetAsync(bar, 0, 2048, stream);

  diag_k<<<8, 256, 0, stream>>>(a_wh, a_wht, diag);

  // XI0: N=4096 -> grid.x=32. XA per layer: N=1024 -> grid.x=8 (a_wx has 1024 rows/layer!)
  gemm128<<<dim3(32, 4), 256, 0, stream>>>(w_ih, xs, XI0, b_ih, b_hh, 512, 1024, 4096);
  gemm128<<<dim3(8, 4), 256, 0, stream>>>(a_wx, xs, XA, nullptr, nullptr, 512, 1024, 2048);
  gemm128<<<dim3(8, 4), 256, 0, stream>>>(a_wx + LSTRIDE / 4, xs, XA + 1024, nullptr, nullptr, 512, 1024, 2048);

  phase1_l0_k<<<30, 256, 0, stream>>>(XI0, tapehG, tapecG, h0p1);
  gemm128<<<dim3(32, 1), 256, 0, stream>>>(w_ih + LSTRIDE, h0p1, G1b, b_ih + 4096, b_hh + 4096, 30, 1024, 4096);
  phase1_l1_k<<<30, 256, 0, stream>>>(G1b, tapehG, tapecG);

  gemm128<<<dim3(32, 1), 256, 0, stream>>>(w_hh, tapehG, P0g, nullptr, nullptr, 30, 2048, 4096);
  gemm128<<<dim3(32, 1), 256, 0, stream>>>(w_hh + LSTRIDE, tapehG + 1024, P1g, nullptr, nullptr, 30, 2048, 4096);

  const float* wihp = w_ih;
  const float* whhp = w_hh;
  const float* bihp = b_ih;
  const float* bhhp = b_hh;
  void* kargs[] = {
    (void*)&wihp, (void*)&whhp, (void*)&bihp, (void*)&bhhp,
    (void*)&diag, (void*)&a_v,  (void*)&XI0,  (void*)&XA,
    (void*)&tapehG, (void*)&tapecG, (void*)&P0g, (void*)&P1g,
    (void*)&scor, (void*)&prevh, (void*)&h0cur, (void*)&h1cur,
    (void*)&outp, (void*)&bar
  };
  hipLaunchCooperativeKernel((void*)scan_fused, dim3(256), dim3(512), kargs, 0, stream);
}

// Round 14
// 3481.172 us; speedup vs baseline: 1.1622x; 1.1622x over previous
//
#include <hip/hip_runtime.h>
#include <math.h>

#define LSTRIDE 4194304   // 4096*1024

// --- fast device math (scan only; precompute uses precise libm) ---
__device__ __forceinline__ float fast_tanh(float x) {
  x = fminf(9.f, fmaxf(-9.f, x));
  float e = __expf(2.f * x);
  return (e - 1.f) * __builtin_amdgcn_rcpf(e + 1.f);
}
__device__ __forceinline__ float fsig(float x) {
  return __builtin_amdgcn_rcpf(1.f + __expf(-x));
}
__device__ __forceinline__ float sigp(float x) { return 1.0f / (1.0f + expf(-x)); }

// Coherent (L2-bypassing) access for ALL cross-WG data => no fences needed.
__device__ __forceinline__ float cload(const float* p) {
  return __hip_atomic_load(p, __ATOMIC_RELAXED, __HIP_MEMORY_SCOPE_AGENT);
}
__device__ __forceinline__ void cstore(float* p, float v) {
  __hip_atomic_store(p, v, __ATOMIC_RELAXED, __HIP_MEMORY_SCOPE_AGENT);
}
__device__ __forceinline__ float2 cload2(const float* p) {
  unsigned long long v = __hip_atomic_load((const unsigned long long*)p,
                                           __ATOMIC_RELAXED, __HIP_MEMORY_SCOPE_AGENT);
  float2 r;
  r.x = __uint_as_float((unsigned)v);
  r.y = __uint_as_float((unsigned)(v >> 32));
  return r;
}
__device__ __forceinline__ void cstore2(float* p, float2 v) {
  unsigned long long u = ((unsigned long long)__float_as_uint(v.y) << 32) |
                         (unsigned long long)__float_as_uint(v.x);
  __hip_atomic_store((unsigned long long*)p, u, __ATOMIC_RELAXED, __HIP_MEMORY_SCOPE_AGENT);
}

// ---------------------------------------------------------------------------
// Generic GEMM: Out[m*ldo + n] = sum_k A[n*1024 + k] * X[m*ldx + k] (+ b1 + b2)
// K fixed = 1024. Grid: (N/64, ceil(M/64)), block 256. Each thread 4x4.
// ---------------------------------------------------------------------------
__global__ __launch_bounds__(256) void gemm_nt(
    const float* __restrict__ A, const float* __restrict__ X, float* __restrict__ Out,
    const float* __restrict__ b1, const float* __restrict__ b2,
    int M, int ldx, int ldo)
{
  __shared__ float As[64][65];
  __shared__ float Xs[64][65];
  const int tid = threadIdx.x;
  const int tn = tid & 15, tm = tid >> 4;
  const int bn = blockIdx.x * 64, bm = blockIdx.y * 64;
  float acc[4][4];
  #pragma unroll
  for (int i = 0; i < 4; ++i)
    #pragma unroll
    for (int j = 0; j < 4; ++j) acc[i][j] = 0.f;

  for (int k0 = 0; k0 < 1024; k0 += 64) {
    #pragma unroll
    for (int r = 0; r < 4; ++r) {
      int linear = r * 1024 + tid * 4;
      int nn = linear >> 6, kk = linear & 63;
      float4 av = *(const float4*)(A + (size_t)(bn + nn) * 1024 + k0 + kk);
      As[nn][kk+0] = av.x; As[nn][kk+1] = av.y; As[nn][kk+2] = av.z; As[nn][kk+3] = av.w;
      float4 xv = make_float4(0.f, 0.f, 0.f, 0.f);
      if (bm + nn < M) xv = *(const float4*)(X + (size_t)(bm + nn) * ldx + k0 + kk);
      Xs[nn][kk+0] = xv.x; Xs[nn][kk+1] = xv.y; Xs[nn][kk+2] = xv.z; Xs[nn][kk+3] = xv.w;
    }
    __syncthreads();
    #pragma unroll 16
    for (int kk = 0; kk < 64; ++kk) {
      float av[4], xv[4];
      #pragma unroll
      for (int u = 0; u < 4; ++u) { av[u] = As[tn*4+u][kk]; xv[u] = Xs[tm*4+u][kk]; }
      #pragma unroll
      for (int i = 0; i < 4; ++i)
        #pragma unroll
        for (int j = 0; j < 4; ++j) acc[i][j] += xv[i] * av[j];
    }
    __syncthreads();
  }
  #pragma unroll
  for (int i = 0; i < 4; ++i) {
    int m = bm + tm * 4 + i;
    if (m >= M) continue;
    #pragma unroll
    for (int j = 0; j < 4; ++j) {
      int n = bn + tn * 4 + j;
      float r = acc[i][j];
      if (b1) r += b1[n];
      if (b2) r += b2[n];
      Out[(size_t)m * ldo + n] = r;
    }
  }
}

__global__ void diag_k(const float* __restrict__ wh, const float* __restrict__ wht,
                       float* __restrict__ diag)
{
  int i = blockIdx.x * 256 + threadIdx.x;
  if (i < 2048) {
    int l = i >> 10, h = i & 1023;
    size_t idx = (size_t)l * 1048576 + (size_t)h * 1025;
    diag[i]        = wh[idx];
    diag[2048 + i] = wht[idx];
  }
}

__global__ __launch_bounds__(256) void phase1_l0_k(const float* __restrict__ XI0,
    float* __restrict__ tapeh, float* __restrict__ tapec, float* __restrict__ h0p1)
{
  int t = blockIdx.x;
  #pragma unroll
  for (int r = 0; r < 4; ++r) {
    int c = threadIdx.x + r * 256;
    float gi = XI0[t*4096 + c];
    float gg = XI0[t*4096 + 2048 + c];
    float go = XI0[t*4096 + 3072 + c];
    float cc = sigp(gi) * tanhf(gg);
    float hh = sigp(go) * tanhf(cc);
    tapeh[t*2048 + c] = hh;
    tapec[t*2048 + c] = cc;
    h0p1[t*1024 + c] = hh;
  }
}

__global__ __launch_bounds__(256) void phase1_l1_k(const float* __restrict__ G1,
    float* __restrict__ tapeh, float* __restrict__ tapec)
{
  int t = blockIdx.x;
  #pragma unroll
  for (int r = 0; r < 4; ++r) {
    int c = threadIdx.x + r * 256;
    float gi = G1[t*4096 + c];
    float gg = G1[t*4096 + 2048 + c];
    float go = G1[t*4096 + 3072 + c];
    float cc = sigp(gi) * tanhf(gg);
    float hh = sigp(go) * tanhf(cc);
    tapeh[t*2048 + 1024 + c] = hh;
    tapec[t*2048 + 1024 + c] = cc;
  }
}

__device__ __forceinline__ float red16(float p) {
  #pragma unroll
  for (int o = 8; o >= 1; o >>= 1) p += __shfl_xor(p, o, 16);
  return p;
}

// ---------------------------------------------------------------------------
// Barrier per group (base stride 256 u32): 8 L1-counters at base[i*16]
// (16 WGs each), flag-counter at base[128]. Flag value after gen g = 8*g.
// Gen g: bootstrap = 1, scan step t completed = t-28.
// ---------------------------------------------------------------------------
__device__ __forceinline__ void arrive(unsigned* __restrict__ base, int gw) {
  asm volatile("s_waitcnt vmcnt(0)" ::: "memory");
  __syncthreads();
  if (threadIdx.x == 0) {
    unsigned o = __hip_atomic_fetch_add(&base[(gw >> 4) * 16], 1u,
                                        __ATOMIC_RELAXED, __HIP_MEMORY_SCOPE_AGENT);
    if (((o + 1) & 15u) == 0u)
      __hip_atomic_fetch_add(&base[128], 1u,
                             __ATOMIC_RELAXED, __HIP_MEMORY_SCOPE_AGENT);
  }
}

__device__ __forceinline__ void waitf(const unsigned* __restrict__ fOwn, unsigned tOwn,
                                      const unsigned* __restrict__ fOth, unsigned tOth) {
  if (threadIdx.x < 2) {
    const unsigned* fp = threadIdx.x ? fOth : fOwn;
    unsigned tgt = threadIdx.x ? tOth : tOwn;
    if (tgt) {
      while (__hip_atomic_load(fp, __ATOMIC_RELAXED, __HIP_MEMORY_SCOPE_AGENT) < tgt)
        __builtin_amdgcn_s_sleep(1);
    }
  }
  __syncthreads();
  asm volatile("" ::: "memory");
}

// ---------------------------------------------------------------------------
// Pipelined persistent scan (round-9 structure, verified). LW=0: WGs 0..127
// (layer-0 chain, barrier group 0). LW=1: WGs 128..255 (layer-1, one step
// behind, barrier group 1). 58 score WGs/group: slot ii=gw>>1, half=gw&1.
// ---------------------------------------------------------------------------
template <int LW>
__device__ __forceinline__ void run_group(
    const int gw,
    const float* __restrict__ wih, const float* __restrict__ whh,
    const float* __restrict__ bih, const float* __restrict__ bhh,
    const float* __restrict__ diag, const float* __restrict__ av,
    const float* __restrict__ XI0, const float* __restrict__ XA,
    const float* __restrict__ tapehG, const float* __restrict__ tapecG,
    const float* __restrict__ Pg,
    float* __restrict__ scoresG, float* __restrict__ prevh,
    float* __restrict__ h0cur, float* __restrict__ h1cur,
    float* __restrict__ outp, unsigned* __restrict__ bar,
    float* tape, float* hA, float* hB, float* Pl, float* tc,
    float* sc2, float* aw, float* gls, float* ihs, float* ncs,
    float* bsum, float* sred)
{
  const int tid = threadIdx.x;
  const int rid = tid >> 4, sub = tid & 15;       // 32 row-slots x 16 lanes
  const int row = ((rid >> 3) << 10) + (gw << 3) + (rid & 7);
  const bool isScore = (gw < 58);
  const int ii = gw >> 1, half = gw & 1;
  const int d = (half << 9) + tid;                // this thread's tail dim
  const int h2 = tid * 2;

  unsigned* __restrict__ barOwn = bar + (LW ? 256 : 0);
  const unsigned* __restrict__ fOwn = barOwn + 128;
  const unsigned* __restrict__ fOth = bar + (LW ? 0 : 256) + 128;

  // ---- one-time init: weights -> VGPRs, P/tape/tc -> LDS ----
  float wA[64];
  float wB[LW ? 64 : 1];
  {
    const float* pa = whh + (size_t)LW * LSTRIDE + (size_t)row * 1024 + sub * 64;
    #pragma unroll
    for (int i = 0; i < 16; ++i) {
      float4 v = ((const float4*)pa)[i];
      wA[4*i] = v.x; wA[4*i+1] = v.y; wA[4*i+2] = v.z; wA[4*i+3] = v.w;
    }
    if (LW) {
      const float* pb = wih + LSTRIDE + (size_t)row * 1024 + sub * 64;
      #pragma unroll
      for (int i = 0; i < 16; ++i) {
        float4 v = ((const float4*)pb)[i];
        wB[4*i] = v.x; wB[4*i+1] = v.y; wB[4*i+2] = v.z; wB[4*i+3] = v.w;
      }
    }
  }
  if (LW && sub == 0) bsum[rid] = bih[4096 + row] + bhh[4096 + row];
  for (int k = tid; k < 960; k += 512) {
    int s = k >> 5, r = k & 31;
    int rr = ((r >> 3) << 10) + (gw << 3) + (r & 7);
    Pl[s * 34 + r] = Pg[s * 4096 + rr];
  }
  for (int k = tid; k < 240; k += 512) {
    int s = k >> 3, c = k & 7;
    tc[s * 9 + c] = tapecG[s * 2048 + LW * 1024 + (gw << 3) + c];
  }
  if (isScore) {
    for (int k = tid; k < 3840; k += 512) {       // 30 slots x 512 dims / 4
      int s = k >> 7, off = (k & 127) << 2;
      *(float4*)&tape[s * 512 + off] =
          *(const float4*)&tapehG[s * 2048 + LW * 1024 + (half << 9) + off];
    }
  }
  // per-thread attn constants: full-dim pair (new-slot) + tail dim d
  const float ddx = diag[LW*1024 + h2],        ddy = diag[LW*1024 + h2 + 1];
  const float ttx = diag[2048 + LW*1024 + h2], tty = diag[2048 + LW*1024 + h2 + 1];
  const float vvx = av[LW*1024 + h2],          vvy = av[LW*1024 + h2 + 1];
  const float ddT = diag[LW*1024 + d];
  const float ttT = diag[2048 + LW*1024 + d];
  const float vvT = av[LW*1024 + d];
  __syncthreads();

  // ---- bootstrap: score partials for t=30 (prev_h = 0) ----
  if (isScore) {
    for (int s = ii; s < 30; s += 29) {
      float xa = XA[(size_t)30 * 2048 + LW * 1024 + d];
      float part = vvT * fast_tanh(ddT * tape[s * 512 + tid] + xa);
      #pragma unroll
      for (int o = 32; o >= 1; o >>= 1) part += __shfl_xor(part, o, 64);
      if ((tid & 63) == 0) sred[tid >> 6] = part;
      __syncthreads();
      if (tid == 0) {
        float tot = 0.f;
        #pragma unroll
        for (int i = 0; i < 8; ++i) tot += sred[i];
        cstore(&scoresG[LW * 64 + 2 * s + half], tot);
      }
      __syncthreads();
    }
  }
  arrive(barOwn, gw);   // gen 1

  for (int t = 30; t < 512; ++t) {
    // ---- prefetch (flag-independent, hides under the wait) ----
    float2 xan = make_float2(0.f, 0.f);
    if (t > 30) xan = *(const float2*)&XA[(size_t)t * 2048 + LW * 1024 + h2];
    float xi = 0.f;
    if (LW == 0 && sub == 0) xi = XI0[(size_t)t * 4096 + row];
    float xaT = 0.f;
    if (isScore && t < 511) xaT = XA[(size_t)(t + 1) * 2048 + LW * 1024 + d];

    // ---- wait (verified generation targets) ----
    unsigned tOwn = 8u * (unsigned)(t - 29);
    unsigned tOth;
    if (LW == 0)
      tOth = (t >= 34) ? 8u * (unsigned)(t - 32) : 0u;  // L1 consumed h0(t-4)
    else
      tOth = 8u * (unsigned)(t - 28);                   // L0 completed t
    waitf(fOwn, tOwn, fOth, tOth);

    const int tmod = t % 30;
    const int pslot = (tmod == 0) ? 29 : tmod - 1;

    // ---- coherent gather ----
    if (tid < 60) sc2[tid] = cload(&scoresG[(t & 1) * 128 + LW * 64 + tid]);
    float2 hva = make_float2(0.f, 0.f), hvb = make_float2(0.f, 0.f),
           ph = make_float2(0.f, 0.f);
    if (LW == 0) {
      if (t > 30) hva = cload2(&h0cur[(size_t)((t - 1) & 3) * 1024 + h2]);
    } else {
      hva = cload2(&h0cur[(size_t)(t & 3) * 1024 + h2]);           // h0(t)
      if (t > 30) hvb = cload2(&h1cur[((t - 1) & 1) * 1024 + h2]); // h1(t-1)
    }
    if (t > 30) ph = cload2(&prevh[((t - 1) & 1) * 2048 + LW * 1024 + h2]);
    {
      int o = (h2 >> 6) * 66 + (h2 & 63);
      if (LW || t > 30) { hA[o] = hva.x; hA[o + 1] = hva.y; }
      if (LW && t > 30) { hB[o] = hvb.x; hB[o + 1] = hvb.y; }
    }
    __syncthreads();

    // ---- new-slot score + tape refresh + P-col matvec (+ ih for L1) ----
    if (t > 30) {
      float2 hn = LW ? hvb : hva;                 // own-layer h(t-1)
      float np = vvx * fast_tanh(ddx * hn.x + xan.x + ttx * ph.x)
               + vvy * fast_tanh(ddy * hn.y + xan.y + tty * ph.y);
      #pragma unroll
      for (int o = 32; o >= 1; o >>= 1) np += __shfl_xor(np, o, 64);
      if ((tid & 63) == 0) sred[tid >> 6] = np;
      if (isScore) {
        int loc = h2 - (half << 9);
        if ((unsigned)loc < 512u) {
          tape[pslot * 512 + loc]     = hn.x;
          tape[pslot * 512 + loc + 1] = hn.y;
        }
      }
      const float* hp = LW ? hB : hA;
      float pc = 0.f;
      #pragma unroll
      for (int i = 0; i < 64; ++i) pc += wA[i] * hp[sub * 66 + i];
      pc = red16(pc);
      if (sub == 0) Pl[pslot * 34 + rid] = pc;
    }
    if (LW) {
      float ih = 0.f;
      #pragma unroll
      for (int i = 0; i < 64; ++i) ih += wB[i] * hA[sub * 66 + i];
      ih = red16(ih);
      if (sub == 0) ihs[rid] = ih + bsum[rid];
    }
    __syncthreads();

    // ---- softmax (wave 0; sum half-partials; fold in new-slot score) ----
    if (tid < 32) {
      float npv = 0.f;
      if (t > 30) {
        float x = (tid < 8) ? sred[tid] : 0.f;
        #pragma unroll
        for (int o = 4; o >= 1; o >>= 1) x += __shfl_xor(x, o, 8);
        npv = __shfl(x, 0, 32);
      }
      float v = (tid < 30) ? sc2[2 * tid] + sc2[2 * tid + 1] : -1e30f;
      if (t > 30 && tid == pslot) v = npv;
      float m = v;
      #pragma unroll
      for (int o = 16; o >= 1; o >>= 1) m = fmaxf(m, __shfl_xor(m, o, 32));
      float e = (tid < 30) ? __expf(v - m) : 0.f;
      float sm = e;
      #pragma unroll
      for (int o = 16; o >= 1; o >>= 1) sm += __shfl_xor(sm, o, 32);
      aw[tid] = e * __builtin_amdgcn_rcpf(sm);
    }
    __syncthreads();

    // ---- gates (alpha-weighted P) + c-tape sums ----
    {
      float p = aw[sub] * Pl[sub * 34 + rid];
      if (sub < 14) p += aw[sub + 16] * Pl[(sub + 16) * 34 + rid];
      p = red16(p);
      if (sub == 0) gls[rid] = p + (LW ? ihs[rid] : xi);
      if (rid < 8) {
        float pn = aw[sub] * tc[sub * 9 + rid];
        if (sub < 14) pn += aw[sub + 16] * tc[(sub + 16) * 9 + rid];
        pn = red16(pn);
        if (sub == 0) ncs[rid] = pn;
      }
    }
    __syncthreads();

    // ---- LSTM cell + publish ----
    if (tid < 8) {
      float gi = gls[tid], gf = gls[8 + tid], gg = gls[16 + tid], go = gls[24 + tid];
      float cv = fsig(gf) * ncs[tid] + fsig(gi) * fast_tanh(gg);
      float hv = fsig(go) * fast_tanh(cv);
      if (LW == 0) {
        cstore(&h0cur[(size_t)(t & 3) * 1024 + (gw << 3) + tid], hv);
      } else {
        outp[(size_t)(t - 30) * 1024 + (gw << 3) + tid] = hv;
        cstore(&h1cur[(t & 1) * 1024 + (gw << 3) + tid], hv);
      }
      tc[tmod * 9 + tid] = cv;
    }

    // ---- score-WG tail: prevh(t) half + one old-slot score partial ----
    if (isScore && t < 511) {
      int ss = tmod + 1 + ii; if (ss >= 30) ss -= 30;
      float acc = 0.f;
      #pragma unroll
      for (int s = 0; s < 30; ++s) acc += aw[s] * tape[s * 512 + tid];
      if (ii == 0) cstore(&prevh[(t & 1) * 2048 + LW * 1024 + d], acc);
      float part = vvT * fast_tanh(ddT * tape[ss * 512 + tid] + xaT + ttT * acc);
      #pragma unroll
      for (int o = 32; o >= 1; o >>= 1) part += __shfl_xor(part, o, 64);
      if ((tid & 63) == 0) sred[tid >> 6] = part;
      __syncthreads();
      if (tid == 0) {
        float tot = 0.f;
        #pragma unroll
        for (int i = 0; i < 8; ++i) tot += sred[i];
        cstore(&scoresG[((t + 1) & 1) * 128 + LW * 64 + 2 * ss + half], tot);
      }
    }

    arrive(barOwn, gw);   // gen t-28
  }
}

__global__ __launch_bounds__(512, 2) void scan_fused(
    const float* __restrict__ wih, const float* __restrict__ whh,
    const float* __restrict__ bih, const float* __restrict__ bhh,
    const float* __restrict__ diag, const float* __restrict__ av,
    const float* __restrict__ XI0, const float* __restrict__ XA,
    const float* __restrict__ tapehG, const float* __restrict__ tapecG,
    const float* __restrict__ P0g, const float* __restrict__ P1g,
    float* __restrict__ scoresG, float* __restrict__ prevh,
    float* __restrict__ h0cur, float* __restrict__ h1cur,
    float* __restrict__ outp, unsigned* __restrict__ bar)
{
  __shared__ float tape[30 * 512];
  __shared__ float hA[16 * 66], hB[16 * 66];
  __shared__ float Pl[30 * 34];
  __shared__ float tc[30 * 9];
  __shared__ float sc2[64], aw[32], gls[32], ihs[32], ncs[8], bsum[32], sred[8];
  if (blockIdx.x < 128)
    run_group<0>(blockIdx.x, wih, whh, bih, bhh, diag, av, XI0, XA, tapehG, tapecG,
                 P0g, scoresG, prevh, h0cur, h1cur, outp, bar,
                 tape, hA, hB, Pl, tc, sc2, aw, gls, ihs, ncs, bsum, sred);
  else
    run_group<1>(blockIdx.x - 128, wih, whh, bih, bhh, diag, av, XI0, XA, tapehG, tapecG,
                 P1g, scoresG, prevh, h0cur, h1cur, outp, bar,
                 tape, hA, hB, Pl, tc, sc2, aw, gls, ihs, ncs, bsum, sred);
}

// ---------------------------------------------------------------------------
extern "C" void kernel_launch(void* const* d_in, const int* in_sizes, int n_in,
                              void* d_out, int out_size, void* d_ws, size_t ws_size,
                              hipStream_t stream) {
  (void)in_sizes; (void)n_in; (void)out_size; (void)ws_size;
  const float* xs    = (const float*)d_in[0];
  const float* w_ih  = (const float*)d_in[1];
  const float* w_hh  = (const float*)d_in[2];
  const float* b_ih  = (const float*)d_in[3];
  const float* b_hh  = (const float*)d_in[4];
  const float* a_wh  = (const float*)d_in[5];
  const float* a_wx  = (const float*)d_in[6];
  const float* a_wht = (const float*)d_in[7];
  const float* a_v   = (const float*)d_in[8];
  float* outp = (float*)d_out;

  float* ws     = (float*)d_ws;
  float* XI0    = ws;                      // 512*4096
  float* XA     = XI0    + 512 * 4096;     // 512*2048
  float* tapehG = XA     + 512 * 2048;     // 30*2048
  float* tapecG = tapehG + 30 * 2048;      // 30*2048
  float* P0g    = tapecG + 30 * 2048;      // 30*4096
  float* P1g    = P0g    + 30 * 4096;      // 30*4096
  float* diag   = P1g    + 30 * 4096;      // 4096
  float* scor   = diag   + 4096;           // 2 parity x 2 group x 64 = 256
  float* prevh  = scor   + 256;            // 2*2048
  float* h0cur  = prevh  + 4096;           // 4*1024 (depth-4)
  float* h1cur  = h0cur  + 4096;           // 2*1024
  float* h0p1   = h1cur  + 2048;           // 30*1024
  float* G1b    = h0p1   + 30 * 1024;      // 30*4096
  unsigned* bar = (unsigned*)(G1b + 30 * 4096);  // 2 groups x 256 u32

  hipMemsetAsync(outp + (size_t)482 * 1024, 0, 30 * 1024 * sizeof(float), stream);
  hipMemsetAsync(bar, 0, 2048, stream);

  diag_k<<<8, 256, 0, stream>>>(a_wh, a_wht, diag);

  // XI0: [512][4096] = w_ih0 @ x_t + biases
  gemm_nt<<<dim3(64, 8), 256, 0, stream>>>(w_ih, xs, XI0, b_ih, b_hh, 512, 1024, 4096);
  // XA: both layers in ONE call (a_wx is contiguous [2048][1024]; out ldo=2048)
  gemm_nt<<<dim3(32, 8), 256, 0, stream>>>(a_wx, xs, XA, nullptr, nullptr, 512, 1024, 2048);

  phase1_l0_k<<<30, 256, 0, stream>>>(XI0, tapehG, tapecG, h0p1);
  gemm_nt<<<dim3(64, 1), 256, 0, stream>>>(w_ih + LSTRIDE, h0p1, G1b, b_ih + 4096, b_hh + 4096, 30, 1024, 4096);
  phase1_l1_k<<<30, 256, 0, stream>>>(G1b, tapehG, tapecG);

  gemm_nt<<<dim3(64, 1), 256, 0, stream>>>(w_hh, tapehG, P0g, nullptr, nullptr, 30, 2048, 4096);
  gemm_nt<<<dim3(64, 1), 256, 0, stream>>>(w_hh + LSTRIDE, tapehG + 1024, P1g, nullptr, nullptr, 30, 2048, 4096);

  const float* wihp = w_ih;
  const float* whhp = w_hh;
  const float* bihp = b_ih;
  const float* bhhp = b_hh;
  void* kargs[] = {
    (void*)&wihp, (void*)&whhp, (void*)&bihp, (void*)&bhhp,
    (void*)&diag, (void*)&a_v,  (void*)&XI0,  (void*)&XA,
    (void*)&tapehG, (void*)&tapecG, (void*)&P0g, (void*)&P1g,
    (void*)&scor, (void*)&prevh, (void*)&h0cur, (void*)&h1cur,
    (void*)&outp, (void*)&bar
  };
  hipLaunchCooperativeKernel((void*)scan_fused, dim3(256), dim3(512), kargs, 0, stream);
}